// Round 4
// baseline (72.318 us; speedup 1.0000x reference)
//
#include <hip/hip_runtime.h>

#define D_MODEL 4096
#define N_HEADS 32
#define HEAD_DIM 128
#define MAX_SEQ 512
#define SPLITS 8
#define SPLIT_LEN (MAX_SEQ / SPLITS)   // 64

// ---------------------------------------------------------------------------
// Fused QKV projection + KV-cache copy.
// Grid = 4096 blocks. Blocks with (bid&3)==3 copy the KV caches (skipping the
// step row); the other 3072 blocks each compute 4 GEMV rows (1 wave/row).
// GEMV wave: stage x in LDS, then issue ALL 16 row loads into a[16] (64 VGPR,
// 16KB in flight) before the dot-product -> deep MLP instead of latency chain.
// ---------------------------------------------------------------------------
__global__ __launch_bounds__(256) void proj_copy(
        const float* __restrict__ Wq, const float* __restrict__ bq,
        const float* __restrict__ Wk, const float* __restrict__ bk,
        const float* __restrict__ Wv, const float* __restrict__ bv,
        const float* __restrict__ query, const float* __restrict__ kvsrc,
        const int* __restrict__ step_p,
        const float4* __restrict__ kb, const float4* __restrict__ vb,
        float* __restrict__ qkv_out,
        float* __restrict__ out_kb, float* __restrict__ out_vb) {
    const int bid = blockIdx.x;

    if ((bid & 3) == 3) {                         // ---- copy role (1024 blocks)
        const int step = *step_p;
        int i = (bid >> 2) * 256 + threadIdx.x;   // [0, 262144), 2 float4 each
#pragma unroll
        for (int t = 0; t < 2; ++t, i += 1024 * 256) {
            const int s = (i >> 5) & (MAX_SEQ - 1);
            if (s != step) {
                ((float4*)out_kb)[i] = kb[i];
                ((float4*)out_vb)[i] = vb[i];
            }
        }
        return;
    }

    // ---- gemv role (3072 blocks, 4 rows each)
    const int gid  = (bid >> 2) * 3 + (bid & 3);  // [0, 3072)
    const int wv   = threadIdx.x >> 6;
    const int lane = threadIdx.x & 63;
    const int r    = gid * 4 + wv;                // virtual row in [0, 12288)
    const int which = r >> 12;                    // 0=q 1=k 2=v (uniform per block)
    const int row   = r & (D_MODEL - 1);

    const float* x = (which == 0) ? query : kvsrc;

    __shared__ float4 xs[D_MODEL / 4];            // 16 KB
    {
        const float4* X = (const float4*)x;
#pragma unroll
        for (int t = 0; t < 4; ++t)
            xs[threadIdx.x + 256 * t] = X[threadIdx.x + 256 * t];
    }
    __syncthreads();

    const float* W = (which == 0) ? Wq : (which == 1) ? Wk : Wv;
    const float* b = (which == 0) ? bq : (which == 1) ? bk : bv;
    const float4* A = (const float4*)(W + (size_t)row * D_MODEL);

    float4 a[16];
#pragma unroll
    for (int i = 0; i < 16; ++i) a[i] = A[i * 64 + lane];   // 16 loads in flight

    float acc = 0.f;
#pragma unroll
    for (int i = 0; i < 16; ++i) {
        const float4 xv = xs[i * 64 + lane];
        acc += a[i].x * xv.x + a[i].y * xv.y + a[i].z * xv.z + a[i].w * xv.w;
    }
#pragma unroll
    for (int off = 32; off > 0; off >>= 1) acc += __shfl_xor(acc, off);

    if (lane == 0) {
        const float v = acc + b[row];
        qkv_out[r] = v;
        if (which != 0) {                         // scatter into step row
            const int step = *step_p;
            float* dst = (which == 1) ? out_kb : out_vb;
            dst[((size_t)(row >> 7) * MAX_SEQ + step) * HEAD_DIM + (row & (HEAD_DIM - 1))] = v;
        }
    }
}

// ---------------------------------------------------------------------------
// Flash-decode split: block = (head, split of 64 positions).
// ---------------------------------------------------------------------------
__global__ void attn_split(const float* __restrict__ q,
                           const float* __restrict__ kb,
                           const float* __restrict__ vb,
                           const int* __restrict__ step_p,
                           float* __restrict__ pm, float* __restrict__ pl,
                           float* __restrict__ po) {
    const int bid = blockIdx.x;
    const int h   = bid >> 3;
    const int sp  = bid & (SPLITS - 1);
    const int tid = threadIdx.x;
    const int n   = *step_p + 1;
    const int s0  = sp * SPLIT_LEN;
    const int cnt = min(SPLIT_LEN, n - s0);

    if (cnt <= 0) {
        if (tid == 0) { pm[bid] = -1e30f; pl[bid] = 0.f; }
        if (tid < HEAD_DIM) po[bid * HEAD_DIM + tid] = 0.f;
        return;
    }

    __shared__ float sq[HEAD_DIM];
    __shared__ float w[SPLIT_LEN];
    __shared__ float pv[2][HEAD_DIM];

    if (tid < HEAD_DIM) sq[tid] = q[h * HEAD_DIM + tid];
    __syncthreads();

    // scores: 4 threads per position, 32 elems each
    {
        const int p = tid >> 2;
        const int g = tid & 3;
        float acc = 0.f;
        if (p < cnt) {
            const float4* krow = (const float4*)(kb + ((size_t)(h * MAX_SEQ + s0 + p)) * HEAD_DIM);
            const float4* q4   = (const float4*)sq;
#pragma unroll
            for (int j = 0; j < 8; ++j) {
                float4 kk = krow[g * 8 + j];
                float4 qq = q4[g * 8 + j];
                acc += kk.x * qq.x + kk.y * qq.y + kk.z * qq.z + kk.w * qq.w;
            }
        }
        acc += __shfl_xor(acc, 1);
        acc += __shfl_xor(acc, 2);
        if ((g == 0) && (p < cnt)) w[p] = acc * 0.08838834764831845f;
    }
    __syncthreads();

    // partial softmax (one wave, cnt <= 64)
    if (tid < 64) {
        float mv = (tid < cnt) ? w[tid] : -1e30f;
#pragma unroll
        for (int off = 32; off > 0; off >>= 1) mv = fmaxf(mv, __shfl_xor(mv, off));
        float e = (tid < cnt) ? __expf(w[tid] - mv) : 0.f;
        if (tid < cnt) w[tid] = e;
        float sum = e;
#pragma unroll
        for (int off = 32; off > 0; off >>= 1) sum += __shfl_xor(sum, off);
        if (tid == 0) { pm[bid] = mv; pl[bid] = sum; }
    }
    __syncthreads();

    // P @ V
    const int d    = tid & (HEAD_DIM - 1);
    const int half = tid >> 7;
    float acc = 0.f;
    for (int s = half; s < cnt; s += 2)
        acc += w[s] * vb[((size_t)(h * MAX_SEQ + s0 + s)) * HEAD_DIM + d];
    pv[half][d] = acc;
    __syncthreads();
    if (tid < HEAD_DIM)
        po[bid * HEAD_DIM + tid] = pv[0][tid] + pv[1][tid];
}

__global__ void attn_combine(const float* __restrict__ pm, const float* __restrict__ pl,
                             const float* __restrict__ po, float* __restrict__ attn_out) {
    const int h = blockIdx.x;
    const int d = threadIdx.x;                    // 128 threads
    float m = -1e30f;
#pragma unroll
    for (int j = 0; j < SPLITS; ++j) m = fmaxf(m, pm[h * SPLITS + j]);
    float l = 0.f, o = 0.f;
#pragma unroll
    for (int j = 0; j < SPLITS; ++j) {
        float sc = __expf(pm[h * SPLITS + j] - m);
        l += pl[h * SPLITS + j] * sc;
        o += po[(h * SPLITS + j) * HEAD_DIM + d] * sc;
    }
    attn_out[h * HEAD_DIM + d] = o / l;
}

// ---------------------------------------------------------------------------
// Output projection: same full-row register-blast structure. 1024 blocks.
// ---------------------------------------------------------------------------
__global__ __launch_bounds__(256) void out_gemv(const float* __restrict__ Wo,
                                                const float* __restrict__ bo,
                                                const float* __restrict__ x,
                                                float* __restrict__ out) {
    const int wv   = threadIdx.x >> 6;
    const int lane = threadIdx.x & 63;
    const int row  = blockIdx.x * 4 + wv;

    __shared__ float4 xs[D_MODEL / 4];            // 16 KB
    {
        const float4* X = (const float4*)x;
#pragma unroll
        for (int t = 0; t < 4; ++t)
            xs[threadIdx.x + 256 * t] = X[threadIdx.x + 256 * t];
    }
    __syncthreads();

    const float4* A = (const float4*)(Wo + (size_t)row * D_MODEL);
    float4 a[16];
#pragma unroll
    for (int i = 0; i < 16; ++i) a[i] = A[i * 64 + lane];

    float acc = 0.f;
#pragma unroll
    for (int i = 0; i < 16; ++i) {
        const float4 xv = xs[i * 64 + lane];
        acc += a[i].x * xv.x + a[i].y * xv.y + a[i].z * xv.z + a[i].w * xv.w;
    }
#pragma unroll
    for (int off = 32; off > 0; off >>= 1) acc += __shfl_xor(acc, off);
    if (lane == 0) out[row] = acc + bo[row];
}

extern "C" void kernel_launch(void* const* d_in, const int* in_sizes, int n_in,
                              void* d_out, int out_size, void* d_ws, size_t ws_size,
                              hipStream_t stream) {
    const float* query  = (const float*)d_in[0];
    const float* kvsrc  = (const float*)d_in[1];
    const int*   step_p = (const int*)d_in[2];
    const float* kb     = (const float*)d_in[3];
    const float* vb     = (const float*)d_in[4];
    const float* Wq     = (const float*)d_in[5];
    const float* bq     = (const float*)d_in[6];
    const float* Wk     = (const float*)d_in[7];
    const float* bk     = (const float*)d_in[8];
    const float* Wv     = (const float*)d_in[9];
    const float* bv     = (const float*)d_in[10];
    const float* Wo     = (const float*)d_in[11];
    const float* bo     = (const float*)d_in[12];

    float* out    = (float*)d_out;                                   // [4096]
    float* out_kb = out + D_MODEL;                                   // [32*512*128]
    float* out_vb = out_kb + N_HEADS * MAX_SEQ * HEAD_DIM;           // [32*512*128]

    float* qkv  = (float*)d_ws;            // q[4096], k_new[4096], v_new[4096]
    float* qv   = qkv;
    float* attn = qkv + 3 * D_MODEL;       // [4096]
    float* pm   = attn + D_MODEL;          // [256]
    float* pl   = pm + N_HEADS * SPLITS;   // [256]
    float* po   = pl + N_HEADS * SPLITS;   // [256*128]

    // 1) fused qkv projection + KV copy (+ step-row scatter)
    proj_copy<<<4096, 256, 0, stream>>>(Wq, bq, Wk, bk, Wv, bv, query, kvsrc,
                                        step_p, (const float4*)kb, (const float4*)vb,
                                        qkv, out_kb, out_vb);

    // 2) flash-decode attention: 32 heads x 8 splits
    attn_split<<<N_HEADS * SPLITS, 256, 0, stream>>>(qv, out_kb, out_vb, step_p, pm, pl, po);
    attn_combine<<<N_HEADS, HEAD_DIM, 0, stream>>>(pm, pl, po, attn);

    // 3) output projection
    out_gemv<<<1024, 256, 0, stream>>>(Wo, bo, attn, out);
}